// Round 15
// baseline (135.115 us; speedup 1.0000x reference)
//
#include <hip/hip_runtime.h>
#include <stdint.h>

typedef __bf16 bf16x8 __attribute__((ext_vector_type(8)));
typedef short short8 __attribute__((ext_vector_type(8)));
typedef float f32x4 __attribute__((ext_vector_type(4)));
typedef float f32x16 __attribute__((ext_vector_type(16)));
typedef unsigned short u16;
typedef unsigned int u32;

// B=2, S=2048, E=1024, H=16, D=64; M = B*S = 4096
#define MROWS 4096
#define EDIM  1024
#define SQ    2048
#define DH    64

#if __has_builtin(__builtin_amdgcn_exp2f)
#define EXP2(x) __builtin_amdgcn_exp2f(x)
#else
#define EXP2(x) exp2f(x)
#endif

__device__ __forceinline__ u16 f2bf(float f) {
  unsigned u = __builtin_bit_cast(unsigned, f);
  return (u16)((u + 0x7FFFu + ((u >> 16) & 1u)) >> 16);
}

__device__ __forceinline__ u32 cvtpk_bf16(float lo, float hi) {
  u32 r;
  asm("v_cvt_pk_bf16_f32 %0, %1, %2" : "=v"(r) : "v"(lo), "v"(hi));
  return r;
}
__device__ __forceinline__ void swap32(u32& a, u32& b) {
  asm("v_permlane32_swap_b32 %0, %1" : "+v"(a), "+v"(b));
}

// ---------- fp32 -> bf16 convert: flattened 1D grid, zero no-op blocks ----
// 8192 blocks exactly: bid<6144 -> activations (3 x 2048 blocks of 2048
// elems), else weights (4 x 512 blocks). Each block: 256 thr x 8 elems.
__global__ __launch_bounds__(256) void cvt_flat_kernel(
    const float* __restrict__ s0, const float* __restrict__ s1,
    const float* __restrict__ s2, const float* __restrict__ s3,
    const float* __restrict__ s4, const float* __restrict__ s5,
    const float* __restrict__ s6,
    u16* __restrict__ d0, u16* __restrict__ d1, u16* __restrict__ d2,
    u16* __restrict__ d3, u16* __restrict__ d4, u16* __restrict__ d5,
    u16* __restrict__ d6) {
  const int bid = blockIdx.x;
  const float* s; u16* d; int blk;
  if (bid < 6144) {
    const int t = bid >> 11;          // /2048
    blk = bid & 2047;
    switch (t) {
      case 0: s = s0; d = d0; break;
      case 1: s = s1; d = d1; break;
      default: s = s2; d = d2; break;
    }
  } else {
    const int t = (bid - 6144) >> 9;  // /512
    blk = (bid - 6144) & 511;
    switch (t) {
      case 0: s = s3; d = d3; break;
      case 1: s = s4; d = d4; break;
      case 2: s = s5; d = d5; break;
      default: s = s6; d = d6; break;
    }
  }
  const int i = (blk * 256 + threadIdx.x) * 8;
  float4 a = *(const float4*)(s + i);
  float4 b = *(const float4*)(s + i + 4);
  short8 r;
  r[0] = (short)f2bf(a.x); r[1] = (short)f2bf(a.y);
  r[2] = (short)f2bf(a.z); r[3] = (short)f2bf(a.w);
  r[4] = (short)f2bf(b.x); r[5] = (short)f2bf(b.y);
  r[6] = (short)f2bf(b.z); r[7] = (short)f2bf(b.w);
  *(short8*)(d + i) = r;
}

// ---------- GEMM core 128x128 (bf16 operands): C = A W^T + bias
template <int OUT_F32>
__device__ __forceinline__ void gemm_core(
    const u16* __restrict__ A, const u16* __restrict__ W,
    const float* __restrict__ bias, void* __restrict__ C,
    int m0, int n0, u16* As, u16* Bs) {
  const int tid = threadIdx.x, lane = tid & 63, w = tid >> 6;
  const int r = lane & 15, g = lane >> 4;
  const int wr = w >> 1, wc = w & 1;
  f32x4 acc[4][4] = {};

  for (int kt = 0; kt < 32; ++kt) {
    const int k0 = kt * 32;
    __syncthreads();
#pragma unroll
    for (int i = 0; i < 2; ++i) {
      int c = i * 256 + tid;
      int row = c >> 2, ko = (c & 3) * 8;
      __builtin_amdgcn_global_load_lds(
          (const __attribute__((address_space(1))) void*)(A + (size_t)(m0 + row) * EDIM + k0 + ko),
          (__attribute__((address_space(3))) void*)(As + (i * 256 + w * 64) * 8), 16, 0, 0);
      __builtin_amdgcn_global_load_lds(
          (const __attribute__((address_space(1))) void*)(W + (size_t)(n0 + row) * EDIM + k0 + ko),
          (__attribute__((address_space(3))) void*)(Bs + (i * 256 + w * 64) * 8), 16, 0, 0);
    }
    __syncthreads();
    bf16x8 af[4], bfv[4];
#pragma unroll
    for (int i = 0; i < 4; ++i) {
      af[i]  = *(const bf16x8*)&As[(wr * 64 + i * 16 + r) * 32 + g * 8];
      bfv[i] = *(const bf16x8*)&Bs[(wc * 64 + i * 16 + r) * 32 + g * 8];
    }
#pragma unroll
    for (int mi = 0; mi < 4; ++mi)
#pragma unroll
      for (int ni = 0; ni < 4; ++ni)
        acc[mi][ni] = __builtin_amdgcn_mfma_f32_16x16x32_bf16(af[mi], bfv[ni], acc[mi][ni], 0, 0, 0);
  }
#pragma unroll
  for (int ni = 0; ni < 4; ++ni) {
    const int col = n0 + wc * 64 + ni * 16 + r;
    const float bv = bias[col];
#pragma unroll
    for (int mi = 0; mi < 4; ++mi) {
#pragma unroll
      for (int rr = 0; rr < 4; ++rr) {
        const int rowm = m0 + wr * 64 + mi * 16 + g * 4 + rr;
        float v = acc[mi][ni][rr] + bv;
        if (OUT_F32) ((float*)C)[(size_t)rowm * EDIM + col] = v;
        else ((u16*)C)[(size_t)rowm * EDIM + col] = f2bf(v);
      }
    }
  }
}

// Q/K/V projections fused: grid (8, 32, 3) = 768 blocks -> 3 blocks/CU
__global__ __launch_bounds__(256) void gemm_qkv(
    const u16* __restrict__ X0, const u16* __restrict__ X1, const u16* __restrict__ X2,
    const u16* __restrict__ W0, const u16* __restrict__ W1, const u16* __restrict__ W2,
    const float* __restrict__ b0, const float* __restrict__ b1, const float* __restrict__ b2,
    u16* __restrict__ C0, u16* __restrict__ C1, u16* __restrict__ C2) {
  __shared__ u16 As[128 * 32];
  __shared__ u16 Bs[128 * 32];
  const u16 *A, *W; const float* bias; u16* C;
  switch (blockIdx.z) {
    case 0: A = X0; W = W0; bias = b0; C = C0; break;
    case 1: A = X1; W = W1; bias = b1; C = C1; break;
    default: A = X2; W = W2; bias = b2; C = C2; break;
  }
  gemm_core<0>(A, W, bias, C, blockIdx.y * 128, blockIdx.x * 128, As, Bs);
}

// ---------- output projection: 128x64 tile -> grid (16,32) = 512 blocks ----
// 2 blocks/CU so one block's MFMA overlaps the other's barrier drain.
__global__ __launch_bounds__(256) void gemm_oproj(
    const u16* __restrict__ A, const u16* __restrict__ W,
    const float* __restrict__ bias, float* __restrict__ C) {
  __shared__ __align__(16) u16 As[128 * 32];
  __shared__ __align__(16) u16 Bs[64 * 32];
  const int tid = threadIdx.x, lane = tid & 63, w = tid >> 6;
  const int r = lane & 15, g = lane >> 4;
  const int m0 = blockIdx.y * 128, n0 = blockIdx.x * 64;
  const int wr = w >> 1, wc = w & 1;
  f32x4 acc[4][2] = {};

  for (int kt = 0; kt < 32; ++kt) {
    const int k0 = kt * 32;
    __syncthreads();
#pragma unroll
    for (int i = 0; i < 2; ++i) {
      const int c = i * 256 + tid;
      const int row = c >> 2, ko = (c & 3) * 8;
      __builtin_amdgcn_global_load_lds(
          (const __attribute__((address_space(1))) void*)(A + (size_t)(m0 + row) * EDIM + k0 + ko),
          (__attribute__((address_space(3))) void*)(As + (i * 256 + w * 64) * 8), 16, 0, 0);
    }
    {
      const int c = tid;
      const int row = c >> 2, ko = (c & 3) * 8;
      __builtin_amdgcn_global_load_lds(
          (const __attribute__((address_space(1))) void*)(W + (size_t)(n0 + row) * EDIM + k0 + ko),
          (__attribute__((address_space(3))) void*)(Bs + (w * 64) * 8), 16, 0, 0);
    }
    __syncthreads();
    bf16x8 af[4], bfv[2];
#pragma unroll
    for (int i = 0; i < 4; ++i)
      af[i] = *(const bf16x8*)&As[(wr * 64 + i * 16 + r) * 32 + g * 8];
#pragma unroll
    for (int i = 0; i < 2; ++i)
      bfv[i] = *(const bf16x8*)&Bs[(wc * 32 + i * 16 + r) * 32 + g * 8];
#pragma unroll
    for (int mi = 0; mi < 4; ++mi)
#pragma unroll
      for (int ni = 0; ni < 2; ++ni)
        acc[mi][ni] = __builtin_amdgcn_mfma_f32_16x16x32_bf16(af[mi], bfv[ni], acc[mi][ni], 0, 0, 0);
  }
#pragma unroll
  for (int ni = 0; ni < 2; ++ni) {
    const int col = n0 + wc * 32 + ni * 16 + r;
    const float bv = bias[col];
#pragma unroll
    for (int mi = 0; mi < 4; ++mi)
#pragma unroll
      for (int rr = 0; rr < 4; ++rr) {
        const int rowm = m0 + wr * 64 + mi * 16 + g * 4 + rr;
        C[(size_t)rowm * EDIM + col] = acc[mi][ni][rr] + bv;
      }
  }
}

// ---------- attention staging helpers (r5-proven config) ----------
__device__ __forceinline__ void k_stage(const u16* __restrict__ Kg, int kt, int tid,
                                        int w, u16* kb) {
#pragma unroll
  for (int ri = 0; ri < 2; ++ri) {
    int idx = ri * 256 + tid, row = idx >> 3, sl = idx & 7;
    __builtin_amdgcn_global_load_lds(
        (const __attribute__((address_space(1))) void*)(
            Kg + (size_t)(kt * 64 + row) * EDIM + ((sl ^ (row & 7)) * 8)),
        (__attribute__((address_space(3))) void*)(kb + (ri * 256 + w * 64) * 8), 16, 0, 0);
  }
}

__device__ __forceinline__ void v_issue(const u16* __restrict__ Vg, int kt, int tid,
                                        u32* vdw) {
  const int vd0 = (tid & 31) * 2, kvc = tid >> 5;
#pragma unroll
  for (int j = 0; j < 8; ++j)
    vdw[j] = *(const u32*)(Vg + (size_t)(kt * 64 + kvc * 8 + j) * EDIM + vd0);
}

__device__ __forceinline__ void v_write(u16* vt, int tid, const u32* vdw) {
  const int vd0 = (tid & 31) * 2, kvc = tid >> 5;
  union { u32 u[4]; short8 s; } lo8, hi8;
#pragma unroll
  for (int i = 0; i < 4; ++i) {
    lo8.u[i] = (vdw[2 * i] & 0xFFFFu) | (vdw[2 * i + 1] << 16);
    hi8.u[i] = (vdw[2 * i] >> 16) | (vdw[2 * i + 1] & 0xFFFF0000u);
  }
  const int sl = kvc ^ (vd0 & 7);
  *(short8*)&vt[vd0 * 64 + sl * 8] = lo8.s;
  *(short8*)&vt[(vd0 + 1) * 64 + (sl ^ 1) * 8] = hi8.s;
}

// ---------- attention compute steps ----------
#define CE_CONST 0.18033688011112042f  // log2(e)/8

__device__ __forceinline__ void qk_step(f32x16 (&st)[2], const u16* kb,
                                        const bf16x8 (&qf)[4], const int (&colA)[4],
                                        int lq) {
  __builtin_amdgcn_s_setprio(1);
#pragma unroll
  for (int t = 0; t < 2; ++t) {
    f32x16 z = {};
#pragma unroll
    for (int f = 0; f < 4; ++f) {
      const bf16x8 ka = *(const bf16x8*)&kb[(t * 32 + lq) * 64 + colA[f]];
      z = __builtin_amdgcn_mfma_f32_32x32x16_bf16(ka, qf[f], z, 0, 0, 0);
    }
    st[t] = z;
  }
  __builtin_amdgcn_s_setprio(0);
}

// online softmax (defer-max, r5-proven scalar arithmetic) + P fragment build
__device__ __forceinline__ void softmax_pb(f32x16 (&st)[2], float& m, float& l,
                                           f32x16 (&accO)[2], bf16x8 (&pb)[4]) {
  float vm = fmaxf(st[0][0], st[0][1]);
#pragma unroll
  for (int t = 0; t < 2; ++t)
#pragma unroll
    for (int rr = (t == 0 ? 2 : 0); rr < 16; ++rr) vm = fmaxf(vm, st[t][rr]);
  vm = fmaxf(vm, __shfl_xor(vm, 32));
  if (!__all(vm <= m + 8.0f)) {  // rare: first tile or large max growth
    const float mn = fmaxf(m, vm);
    const float scl = EXP2((m - mn) * CE_CONST);
    m = mn;
    l *= scl;
#pragma unroll
    for (int dt = 0; dt < 2; ++dt)
#pragma unroll
      for (int rr = 0; rr < 16; ++rr) accO[dt][rr] *= scl;
  }
  const float mc = m * CE_CONST;
  float ts = 0.f;
#pragma unroll
  for (int t = 0; t < 2; ++t)
#pragma unroll
    for (int rr = 0; rr < 16; ++rr) {
      float pv = EXP2(st[t][rr] * CE_CONST - mc);
      st[t][rr] = pv;
      ts += pv;
    }
  ts += __shfl_xor(ts, 32);
  l += ts;
#pragma unroll
  for (int t = 0; t < 2; ++t)
#pragma unroll
    for (int kh = 0; kh < 2; ++kh) {
      const int rb = kh * 8;
      u32 a0 = cvtpk_bf16(st[t][rb + 0], st[t][rb + 1]);
      u32 b0 = cvtpk_bf16(st[t][rb + 4], st[t][rb + 5]);
      swap32(a0, b0);
      u32 a1 = cvtpk_bf16(st[t][rb + 2], st[t][rb + 3]);
      u32 b1 = cvtpk_bf16(st[t][rb + 6], st[t][rb + 7]);
      swap32(a1, b1);
      union { u32 u[4]; bf16x8 v; } pu;
      pu.u[0] = a0; pu.u[1] = a1; pu.u[2] = b0; pu.u[3] = b1;
      pb[t * 2 + kh] = pu.v;
    }
}

__device__ __forceinline__ void pv_step(f32x16 (&accO)[2], const bf16x8 (&pb)[4],
                                        const u16* vt, const int (&colA)[4], int lq) {
  __builtin_amdgcn_s_setprio(1);
#pragma unroll
  for (int dt = 0; dt < 2; ++dt)
#pragma unroll
    for (int ks = 0; ks < 4; ++ks) {
      const bf16x8 va = *(const bf16x8*)&vt[(dt * 32 + lq) * 64 + colA[ks]];
      accO[dt] = __builtin_amdgcn_mfma_f32_32x32x16_bf16(va, pb[ks], accO[dt], 0, 0, 0);
    }
  __builtin_amdgcn_s_setprio(0);
}

// ---------- flash attention (r5-proven): swapped-operand 32x32 MFMA, T15 ----
// grid: 512 blocks (16 qb x 32 bh), 4 waves, 32 q/wave, KVBLK=64.
__global__ __launch_bounds__(256) void attn2_kernel(
    const u16* __restrict__ Q, const u16* __restrict__ K,
    const u16* __restrict__ V, u16* __restrict__ O) {
  __shared__ __align__(16) u16 KB[2][64 * 64];
  __shared__ __align__(16) u16 VT[3][64 * 64];
  const int tid = threadIdx.x, lane = tid & 63, w = tid >> 6;
  const int lq = lane & 31, hi = lane >> 5;
  const int bid = blockIdx.x;
  const int b2 = (bid & 7) * 64 + (bid >> 3);   // XCD-chunked
  const int qb = b2 & 15, bh = b2 >> 4;
  const int b = bh >> 4, h = bh & 15;
  const u16* Qg = Q + (size_t)b * SQ * EDIM + h * DH;
  const u16* Kg = K + (size_t)b * SQ * EDIM + h * DH;
  const u16* Vg = V + (size_t)b * SQ * EDIM + h * DH;
  const int q0 = qb * 128 + w * 32;

  bf16x8 qf[4];
#pragma unroll
  for (int f = 0; f < 4; ++f)
    qf[f] = *(const bf16x8*)(Qg + (size_t)(q0 + lq) * EDIM + f * 16 + hi * 8);

  const int swz = (lq & 7) << 4;
  int colA[4];
#pragma unroll
  for (int f = 0; f < 4; ++f) colA[f] = ((f * 32 + hi * 16) ^ swz) >> 1;

  f32x16 accO[2] = {};
  f32x16 stA[2], stB[2];
  bf16x8 pb[4];
  float m = -3e38f, l = 0.f;
  u32 vdw[8];

  k_stage(Kg, 0, tid, w, KB[0]);
  v_issue(Vg, 0, tid, vdw);
  v_write(VT[0], tid, vdw);
  __syncthreads();
  k_stage(Kg, 1, tid, w, KB[1]);
  v_issue(Vg, 1, tid, vdw);
  qk_step(stA, KB[0], qf, colA, lq);
  v_write(VT[1], tid, vdw);
  __syncthreads();

#define ATTN_BODY(T, SP, SN)                                                  \
  {                                                                           \
    if ((T) < 31) { k_stage(Kg, (T) + 1, tid, w, KB[((T) + 1) & 1]);          \
                    v_issue(Vg, (T) + 1, tid, vdw); }                         \
    qk_step(SN, KB[(T) & 1], qf, colA, lq);                                   \
    softmax_pb(SP, m, l, accO, pb);                                           \
    pv_step(accO, pb, VT[((T) - 1) % 3], colA, lq);                           \
    if ((T) < 31) v_write(VT[((T) + 1) % 3], tid, vdw);                       \
    __syncthreads();                                                          \
  }

  for (int t = 1; t < 31; t += 2) {
    ATTN_BODY(t, stA, stB);
    ATTN_BODY(t + 1, stB, stA);
  }
  ATTN_BODY(31, stA, stB);
#undef ATTN_BODY

  softmax_pb(stB, m, l, accO, pb);
  pv_step(accO, pb, VT[31 % 3], colA, lq);

  const float rinv = 1.0f / l;
  u16* Ost = (u16*)KB;
#pragma unroll
  for (int dt = 0; dt < 2; ++dt)
#pragma unroll
    for (int rr = 0; rr < 16; ++rr) {
      const int d = dt * 32 + (rr & 3) + 8 * (rr >> 2) + 4 * hi;
      Ost[w * 2048 + lq * 64 + (d ^ ((lq & 7) << 3))] = f2bf(accO[dt][rr] * rinv);
    }
  __syncthreads();
#pragma unroll
  for (int ri = 0; ri < 4; ++ri) {
    const int idx = ri * 256 + tid;
    const int w2 = idx >> 8, q = (idx >> 3) & 31, c = idx & 7;
    short8 o = *(const short8*)&Ost[w2 * 2048 + q * 64 + ((c ^ (q & 7)) * 8)];
    *(short8*)(O + (size_t)(b * SQ + qb * 128 + w2 * 32 + q) * EDIM + h * DH + c * 8) = o;
  }
}

extern "C" void kernel_launch(void* const* d_in, const int* in_sizes, int n_in,
                              void* d_out, int out_size, void* d_ws, size_t ws_size,
                              hipStream_t stream) {
  (void)in_sizes; (void)n_in; (void)out_size; (void)ws_size;
  const float* query = (const float*)d_in[0];
  const float* key   = (const float*)d_in[1];
  const float* value = (const float*)d_in[2];
  const float* q_w = (const float*)d_in[3];
  const float* q_b = (const float*)d_in[4];
  const float* k_w = (const float*)d_in[5];
  const float* k_b = (const float*)d_in[6];
  const float* v_w = (const float*)d_in[7];
  const float* v_b = (const float*)d_in[8];
  const float* o_w = (const float*)d_in[9];
  const float* o_b = (const float*)d_in[10];

  u16* ws = (u16*)d_ws;
  const size_t NX = (size_t)MROWS * EDIM;  // 4M
  const size_t NW = (size_t)EDIM * EDIM;   // 1M
  u16* Xq = ws;
  u16* Xk = Xq + NX;
  u16* Xv = Xk + NX;
  u16* Wq = Xv + NX;
  u16* Wk = Wq + NW;
  u16* Wv = Wk + NW;
  u16* Wo = Wv + NW;
  u16* Qp = Wo + NW;
  u16* Kp = Qp + NX;
  u16* Vp = Kp + NX;
  u16* At = Xq;  // overlay: Xq dead after Q projection

  // flattened cvt: exactly 8192 useful blocks (no no-op dispatch slots)
  cvt_flat_kernel<<<8192, 256, 0, stream>>>(
      query, key, value, q_w, k_w, v_w, o_w,
      Xq, Xk, Xv, Wq, Wk, Wv, Wo);

  gemm_qkv<<<dim3(8, 32, 3), 256, 0, stream>>>(
      Xq, Xk, Xv, Wq, Wk, Wv, q_b, k_b, v_b, Qp, Kp, Vp);

  attn2_kernel<<<512, 256, 0, stream>>>(Qp, Kp, Vp, At);

  gemm_oproj<<<dim3(16, 32), 256, 0, stream>>>(At, Wo, o_b, (float*)d_out);
}

// Round 16
// 127.722 us; speedup vs baseline: 1.0579x; 1.0579x over previous
//
#include <hip/hip_runtime.h>
#include <stdint.h>

typedef __bf16 bf16x8 __attribute__((ext_vector_type(8)));
typedef short short8 __attribute__((ext_vector_type(8)));
typedef float f32x4 __attribute__((ext_vector_type(4)));
typedef float f32x16 __attribute__((ext_vector_type(16)));
typedef unsigned short u16;
typedef unsigned int u32;

// B=2, S=2048, E=1024, H=16, D=64; M = B*S = 4096
#define MROWS 4096
#define EDIM  1024
#define SQ    2048
#define DH    64

#if __has_builtin(__builtin_amdgcn_exp2f)
#define EXP2(x) __builtin_amdgcn_exp2f(x)
#else
#define EXP2(x) exp2f(x)
#endif

__device__ __forceinline__ u16 f2bf(float f) {
  unsigned u = __builtin_bit_cast(unsigned, f);
  return (u16)((u + 0x7FFFu + ((u >> 16) & 1u)) >> 16);
}

__device__ __forceinline__ u32 cvtpk_bf16(float lo, float hi) {
  u32 r;
  asm("v_cvt_pk_bf16_f32 %0, %1, %2" : "=v"(r) : "v"(lo), "v"(hi));
  return r;
}
__device__ __forceinline__ void swap32(u32& a, u32& b) {
  asm("v_permlane32_swap_b32 %0, %1" : "+v"(a), "+v"(b));
}

// ---------- fp32 -> bf16 convert: flattened 1D grid, zero no-op blocks ----
__global__ __launch_bounds__(256) void cvt_flat_kernel(
    const float* __restrict__ s0, const float* __restrict__ s1,
    const float* __restrict__ s2, const float* __restrict__ s3,
    const float* __restrict__ s4, const float* __restrict__ s5,
    const float* __restrict__ s6,
    u16* __restrict__ d0, u16* __restrict__ d1, u16* __restrict__ d2,
    u16* __restrict__ d3, u16* __restrict__ d4, u16* __restrict__ d5,
    u16* __restrict__ d6) {
  const int bid = blockIdx.x;
  const float* s; u16* d; int blk;
  if (bid < 6144) {
    const int t = bid >> 11;
    blk = bid & 2047;
    switch (t) {
      case 0: s = s0; d = d0; break;
      case 1: s = s1; d = d1; break;
      default: s = s2; d = d2; break;
    }
  } else {
    const int t = (bid - 6144) >> 9;
    blk = (bid - 6144) & 511;
    switch (t) {
      case 0: s = s3; d = d3; break;
      case 1: s = s4; d = d4; break;
      case 2: s = s5; d = d5; break;
      default: s = s6; d = d6; break;
    }
  }
  const int i = (blk * 256 + threadIdx.x) * 8;
  float4 a = *(const float4*)(s + i);
  float4 b = *(const float4*)(s + i + 4);
  short8 r;
  r[0] = (short)f2bf(a.x); r[1] = (short)f2bf(a.y);
  r[2] = (short)f2bf(a.z); r[3] = (short)f2bf(a.w);
  r[4] = (short)f2bf(b.x); r[5] = (short)f2bf(b.y);
  r[6] = (short)f2bf(b.z); r[7] = (short)f2bf(b.w);
  *(short8*)(d + i) = r;
}

// ---------- GEMM core 128x128 (bf16 operands): C = A W^T + bias
template <int OUT_F32>
__device__ __forceinline__ void gemm_core(
    const u16* __restrict__ A, const u16* __restrict__ W,
    const float* __restrict__ bias, void* __restrict__ C,
    int m0, int n0, u16* As, u16* Bs) {
  const int tid = threadIdx.x, lane = tid & 63, w = tid >> 6;
  const int r = lane & 15, g = lane >> 4;
  const int wr = w >> 1, wc = w & 1;
  f32x4 acc[4][4] = {};

  for (int kt = 0; kt < 32; ++kt) {
    const int k0 = kt * 32;
    __syncthreads();
#pragma unroll
    for (int i = 0; i < 2; ++i) {
      int c = i * 256 + tid;
      int row = c >> 2, ko = (c & 3) * 8;
      __builtin_amdgcn_global_load_lds(
          (const __attribute__((address_space(1))) void*)(A + (size_t)(m0 + row) * EDIM + k0 + ko),
          (__attribute__((address_space(3))) void*)(As + (i * 256 + w * 64) * 8), 16, 0, 0);
      __builtin_amdgcn_global_load_lds(
          (const __attribute__((address_space(1))) void*)(W + (size_t)(n0 + row) * EDIM + k0 + ko),
          (__attribute__((address_space(3))) void*)(Bs + (i * 256 + w * 64) * 8), 16, 0, 0);
    }
    __syncthreads();
    bf16x8 af[4], bfv[4];
#pragma unroll
    for (int i = 0; i < 4; ++i) {
      af[i]  = *(const bf16x8*)&As[(wr * 64 + i * 16 + r) * 32 + g * 8];
      bfv[i] = *(const bf16x8*)&Bs[(wc * 64 + i * 16 + r) * 32 + g * 8];
    }
#pragma unroll
    for (int mi = 0; mi < 4; ++mi)
#pragma unroll
      for (int ni = 0; ni < 4; ++ni)
        acc[mi][ni] = __builtin_amdgcn_mfma_f32_16x16x32_bf16(af[mi], bfv[ni], acc[mi][ni], 0, 0, 0);
  }
#pragma unroll
  for (int ni = 0; ni < 4; ++ni) {
    const int col = n0 + wc * 64 + ni * 16 + r;
    const float bv = bias[col];
#pragma unroll
    for (int mi = 0; mi < 4; ++mi) {
#pragma unroll
      for (int rr = 0; rr < 4; ++rr) {
        const int rowm = m0 + wr * 64 + mi * 16 + g * 4 + rr;
        float v = acc[mi][ni][rr] + bv;
        if (OUT_F32) ((float*)C)[(size_t)rowm * EDIM + col] = v;
        else ((u16*)C)[(size_t)rowm * EDIM + col] = f2bf(v);
      }
    }
  }
}

// Q/K/V projections fused: grid (8, 32, 3) = 768 blocks -> 3 blocks/CU
__global__ __launch_bounds__(256) void gemm_qkv(
    const u16* __restrict__ X0, const u16* __restrict__ X1, const u16* __restrict__ X2,
    const u16* __restrict__ W0, const u16* __restrict__ W1, const u16* __restrict__ W2,
    const float* __restrict__ b0, const float* __restrict__ b1, const float* __restrict__ b2,
    u16* __restrict__ C0, u16* __restrict__ C1, u16* __restrict__ C2) {
  __shared__ u16 As[128 * 32];
  __shared__ u16 Bs[128 * 32];
  const u16 *A, *W; const float* bias; u16* C;
  switch (blockIdx.z) {
    case 0: A = X0; W = W0; bias = b0; C = C0; break;
    case 1: A = X1; W = W1; bias = b1; C = C1; break;
    default: A = X2; W = W2; bias = b2; C = C2; break;
  }
  gemm_core<0>(A, W, bias, C, blockIdx.y * 128, blockIdx.x * 128, As, Bs);
}

// ---------- output projection: 128x64 tile -> grid (16,32) = 512 blocks ----
__global__ __launch_bounds__(256) void gemm_oproj(
    const u16* __restrict__ A, const u16* __restrict__ W,
    const float* __restrict__ bias, float* __restrict__ C) {
  __shared__ __align__(16) u16 As[128 * 32];
  __shared__ __align__(16) u16 Bs[64 * 32];
  const int tid = threadIdx.x, lane = tid & 63, w = tid >> 6;
  const int r = lane & 15, g = lane >> 4;
  const int m0 = blockIdx.y * 128, n0 = blockIdx.x * 64;
  const int wr = w >> 1, wc = w & 1;
  f32x4 acc[4][2] = {};

  for (int kt = 0; kt < 32; ++kt) {
    const int k0 = kt * 32;
    __syncthreads();
#pragma unroll
    for (int i = 0; i < 2; ++i) {
      const int c = i * 256 + tid;
      const int row = c >> 2, ko = (c & 3) * 8;
      __builtin_amdgcn_global_load_lds(
          (const __attribute__((address_space(1))) void*)(A + (size_t)(m0 + row) * EDIM + k0 + ko),
          (__attribute__((address_space(3))) void*)(As + (i * 256 + w * 64) * 8), 16, 0, 0);
    }
    {
      const int c = tid;
      const int row = c >> 2, ko = (c & 3) * 8;
      __builtin_amdgcn_global_load_lds(
          (const __attribute__((address_space(1))) void*)(W + (size_t)(n0 + row) * EDIM + k0 + ko),
          (__attribute__((address_space(3))) void*)(Bs + (w * 64) * 8), 16, 0, 0);
    }
    __syncthreads();
    bf16x8 af[4], bfv[2];
#pragma unroll
    for (int i = 0; i < 4; ++i)
      af[i] = *(const bf16x8*)&As[(wr * 64 + i * 16 + r) * 32 + g * 8];
#pragma unroll
    for (int i = 0; i < 2; ++i)
      bfv[i] = *(const bf16x8*)&Bs[(wc * 32 + i * 16 + r) * 32 + g * 8];
#pragma unroll
    for (int mi = 0; mi < 4; ++mi)
#pragma unroll
      for (int ni = 0; ni < 2; ++ni)
        acc[mi][ni] = __builtin_amdgcn_mfma_f32_16x16x32_bf16(af[mi], bfv[ni], acc[mi][ni], 0, 0, 0);
  }
#pragma unroll
  for (int ni = 0; ni < 2; ++ni) {
    const int col = n0 + wc * 32 + ni * 16 + r;
    const float bv = bias[col];
#pragma unroll
    for (int mi = 0; mi < 4; ++mi)
#pragma unroll
      for (int rr = 0; rr < 4; ++rr) {
        const int rowm = m0 + wr * 64 + mi * 16 + g * 4 + rr;
        C[(size_t)rowm * EDIM + col] = acc[mi][ni][rr] + bv;
      }
  }
}

// ---------- attention staging helpers (per-split: 256 threads, KVBLK=64) ----
// lt = local tid within split (0..255), lw = local wave (0..3). Verified in r9.
__device__ __forceinline__ void k_stage(const u16* __restrict__ Kg, int kt, int lt,
                                        int lw, u16* kb) {
#pragma unroll
  for (int ri = 0; ri < 2; ++ri) {
    int idx = ri * 256 + lt, row = idx >> 3, sl = idx & 7;
    __builtin_amdgcn_global_load_lds(
        (const __attribute__((address_space(1))) void*)(
            Kg + (size_t)(kt * 64 + row) * EDIM + ((sl ^ (row & 7)) * 8)),
        (__attribute__((address_space(3))) void*)(kb + (ri * 256 + lw * 64) * 8), 16, 0, 0);
  }
}

__device__ __forceinline__ void v_issue(const u16* __restrict__ Vg, int kt, int lt,
                                        u32* vdw) {
  const int vd0 = (lt & 31) * 2, kvc = lt >> 5;  // kvc 0..7
#pragma unroll
  for (int j = 0; j < 8; ++j)
    vdw[j] = *(const u32*)(Vg + (size_t)(kt * 64 + kvc * 8 + j) * EDIM + vd0);
}

__device__ __forceinline__ void v_write(u16* vt, int lt, const u32* vdw) {
  const int vd0 = (lt & 31) * 2, kvc = lt >> 5;
  union { u32 u[4]; short8 s; } lo8, hi8;
#pragma unroll
  for (int i = 0; i < 4; ++i) {
    lo8.u[i] = (vdw[2 * i] & 0xFFFFu) | (vdw[2 * i + 1] << 16);
    hi8.u[i] = (vdw[2 * i] >> 16) | (vdw[2 * i + 1] & 0xFFFF0000u);
  }
  const int sl = kvc ^ (vd0 & 7);
  *(short8*)&vt[vd0 * 64 + sl * 8] = lo8.s;
  *(short8*)&vt[(vd0 + 1) * 64 + (sl ^ 1) * 8] = hi8.s;
}

// ---------- attention compute steps ----------
#define CE_CONST 0.18033688011112042f  // log2(e)/8

__device__ __forceinline__ void qk_step(f32x16 (&st)[2], const u16* kb,
                                        const bf16x8 (&qf)[4], const int (&colA)[4],
                                        int lq) {
  __builtin_amdgcn_s_setprio(1);
#pragma unroll
  for (int t = 0; t < 2; ++t) {
    f32x16 z = {};
#pragma unroll
    for (int f = 0; f < 4; ++f) {
      const bf16x8 ka = *(const bf16x8*)&kb[(t * 32 + lq) * 64 + colA[f]];
      z = __builtin_amdgcn_mfma_f32_32x32x16_bf16(ka, qf[f], z, 0, 0, 0);
    }
    st[t] = z;
  }
  __builtin_amdgcn_s_setprio(0);
}

// online softmax (defer-max, r5-proven scalar arithmetic) + P fragment build
__device__ __forceinline__ void softmax_pb(f32x16 (&st)[2], float& m, float& l,
                                           f32x16 (&accO)[2], bf16x8 (&pb)[4]) {
  float vm = fmaxf(st[0][0], st[0][1]);
#pragma unroll
  for (int t = 0; t < 2; ++t)
#pragma unroll
    for (int rr = (t == 0 ? 2 : 0); rr < 16; ++rr) vm = fmaxf(vm, st[t][rr]);
  vm = fmaxf(vm, __shfl_xor(vm, 32));
  if (!__all(vm <= m + 8.0f)) {  // rare: first tile or large max growth
    const float mn = fmaxf(m, vm);
    const float scl = EXP2((m - mn) * CE_CONST);
    m = mn;
    l *= scl;
#pragma unroll
    for (int dt = 0; dt < 2; ++dt)
#pragma unroll
      for (int rr = 0; rr < 16; ++rr) accO[dt][rr] *= scl;
  }
  const float mc = m * CE_CONST;
  float ts = 0.f;
#pragma unroll
  for (int t = 0; t < 2; ++t)
#pragma unroll
    for (int rr = 0; rr < 16; ++rr) {
      float pv = EXP2(st[t][rr] * CE_CONST - mc);
      st[t][rr] = pv;
      ts += pv;
    }
  ts += __shfl_xor(ts, 32);
  l += ts;
#pragma unroll
  for (int t = 0; t < 2; ++t)
#pragma unroll
    for (int kh = 0; kh < 2; ++kh) {
      const int rb = kh * 8;
      u32 a0 = cvtpk_bf16(st[t][rb + 0], st[t][rb + 1]);
      u32 b0 = cvtpk_bf16(st[t][rb + 4], st[t][rb + 5]);
      swap32(a0, b0);
      u32 a1 = cvtpk_bf16(st[t][rb + 2], st[t][rb + 3]);
      u32 b1 = cvtpk_bf16(st[t][rb + 6], st[t][rb + 7]);
      swap32(a1, b1);
      union { u32 u[4]; bf16x8 v; } pu;
      pu.u[0] = a0; pu.u[1] = a1; pu.u[2] = b0; pu.u[3] = b1;
      pb[t * 2 + kh] = pu.v;
    }
}

__device__ __forceinline__ void pv_step(f32x16 (&accO)[2], const bf16x8 (&pb)[4],
                                        const u16* vt, const int (&colA)[4], int lq) {
  __builtin_amdgcn_s_setprio(1);
#pragma unroll
  for (int dt = 0; dt < 2; ++dt)
#pragma unroll
    for (int ks = 0; ks < 4; ++ks) {
      const bf16x8 va = *(const bf16x8*)&vt[(dt * 32 + lq) * 64 + colA[ks]];
      accO[dt] = __builtin_amdgcn_mfma_f32_32x32x16_bf16(va, pb[ks], accO[dt], 0, 0, 0);
    }
  __builtin_amdgcn_s_setprio(0);
}

// ---------- flash attention: in-block kv-split, 64KB LDS -> 4 waves/SIMD ----
// grid: 512 blocks (16 qb x 32 bh), 512 threads = 8 waves = 4 q-waves x 2
// kv-splits. vs r9: VT trimmed to 2-deep (single-score-buffer r3-proven body)
// so LDS = 64KB -> 2 blocks/CU x 8 waves = 16 waves/CU = 4 waves/SIMD
// (r8/r9 were LDS-capped and never reached this). Exact split merge (r9).
__global__ __launch_bounds__(512) void attn3_kernel(
    const u16* __restrict__ Q, const u16* __restrict__ K,
    const u16* __restrict__ V, u16* __restrict__ O) {
  __shared__ __align__(16) u16 KB[2][2][64 * 64];  // [split][dbuf]  32KB
  __shared__ __align__(16) u16 VT[2][2][64 * 64];  // [split][dbuf]  32KB
  const int tid = threadIdx.x, lane = tid & 63, w = tid >> 6;  // w 0..7
  const int sp = w >> 2, qw = w & 3, lt = tid & 255;
  const int lq = lane & 31, hi = lane >> 5;
  const int bid = blockIdx.x;
  const int b2 = (bid & 7) * 64 + (bid >> 3);   // XCD-chunked
  const int qb = b2 & 15, bh = b2 >> 4;
  const int b = bh >> 4, h = bh & 15;
  const u16* Qg = Q + (size_t)b * SQ * EDIM + h * DH;
  const u16* Kg = K + (size_t)b * SQ * EDIM + h * DH + (size_t)sp * 1024 * EDIM;
  const u16* Vg = V + (size_t)b * SQ * EDIM + h * DH + (size_t)sp * 1024 * EDIM;
  const int q0 = qb * 128 + qw * 32;

  bf16x8 qf[4];
#pragma unroll
  for (int f = 0; f < 4; ++f)
    qf[f] = *(const bf16x8*)(Qg + (size_t)(q0 + lq) * EDIM + f * 16 + hi * 8);

  const int swz = (lq & 7) << 4;
  int colA[4];
#pragma unroll
  for (int f = 0; f < 4; ++f) colA[f] = ((f * 32 + hi * 16) ^ swz) >> 1;

  f32x16 accO[2] = {};
  f32x16 st[2];
  bf16x8 pb[4];
  float m = -3e38f, l = 0.f;
  u32 vdw[8];

  // prologue: stage tile 0 (per split)
  k_stage(Kg, 0, lt, qw, KB[sp][0]);
  v_issue(Vg, 0, lt, vdw);
  v_write(VT[sp][0], lt, vdw);
  __syncthreads();

  // r3-proven single-score-buffer body, 16 tiles per split.
  // Hazards: body T reads slot T&1, writes slot (T+1)&1; barrier separates
  // body T's writes from body T+1's reads and body T-1's reads of (T+1)&1.
  for (int T = 0; T < 16; ++T) {
    if (T < 15) {
      k_stage(Kg, T + 1, lt, qw, KB[sp][(T + 1) & 1]);
      v_issue(Vg, T + 1, lt, vdw);
    }
    qk_step(st, KB[sp][T & 1], qf, colA, lq);
    softmax_pb(st, m, l, accO, pb);
    pv_step(accO, pb, VT[sp][T & 1], colA, lq);
    if (T < 15) v_write(VT[sp][(T + 1) & 1], lt, vdw);
    __syncthreads();
  }

  // ---- merge split 1 into split 0 (exact; r9-verified): rotated LDS layout
  float* mrgf = (float*)&KB[0][0][0];   // 32KB = 4 qw x 32 q x 64 d f32
  float* sttf = (float*)&VT[0][0][0];   // 1KB stats
  if (sp == 1) {
#pragma unroll
    for (int dt = 0; dt < 2; ++dt)
#pragma unroll
      for (int rr = 0; rr < 16; ++rr) {
        const int d = dt * 32 + (rr & 3) + 8 * (rr >> 2) + 4 * hi;
        mrgf[(qw * 32 + lq) * 64 + ((d + 2 * lq) & 63)] = accO[dt][rr];
      }
    if (lane < 32) {
      sttf[(qw * 32 + lq) * 2 + 0] = m;
      sttf[(qw * 32 + lq) * 2 + 1] = l;
    }
  }
  __syncthreads();
  if (sp == 0) {
    const float m1 = sttf[(qw * 32 + lq) * 2 + 0];
    const float l1 = sttf[(qw * 32 + lq) * 2 + 1];
    const float ms = fmaxf(m, m1);
    const float e0 = EXP2((m - ms) * CE_CONST);
    const float e1 = EXP2((m1 - ms) * CE_CONST);
    l = l * e0 + l1 * e1;
#pragma unroll
    for (int dt = 0; dt < 2; ++dt)
#pragma unroll
      for (int rr = 0; rr < 16; ++rr) {
        const int d = dt * 32 + (rr & 3) + 8 * (rr >> 2) + 4 * hi;
        accO[dt][rr] = accO[dt][rr] * e0 +
                       mrgf[(qw * 32 + lq) * 64 + ((d + 2 * lq) & 63)] * e1;
      }
  }
  __syncthreads();  // mrg reads done before Ost overwrites the region

  // ---- O^T regs -> swizzled LDS -> coalesced global store
  u16* Ost = (u16*)KB;  // 16KB: 4 q-waves x 32q x 64d
  if (sp == 0) {
    const float rinv = 1.0f / l;
#pragma unroll
    for (int dt = 0; dt < 2; ++dt)
#pragma unroll
      for (int rr = 0; rr < 16; ++rr) {
        const int d = dt * 32 + (rr & 3) + 8 * (rr >> 2) + 4 * hi;
        Ost[qw * 2048 + lq * 64 + (d ^ ((lq & 7) << 3))] = f2bf(accO[dt][rr] * rinv);
      }
  }
  __syncthreads();
#pragma unroll
  for (int ri = 0; ri < 2; ++ri) {
    const int idx = ri * 512 + tid;
    const int w2 = idx >> 8, q = (idx >> 3) & 31, c = idx & 7;
    short8 o = *(const short8*)&Ost[w2 * 2048 + q * 64 + ((c ^ (q & 7)) * 8)];
    *(short8*)(O + (size_t)(b * SQ + qb * 128 + w2 * 32 + q) * EDIM + h * DH + c * 8) = o;
  }
}

extern "C" void kernel_launch(void* const* d_in, const int* in_sizes, int n_in,
                              void* d_out, int out_size, void* d_ws, size_t ws_size,
                              hipStream_t stream) {
  (void)in_sizes; (void)n_in; (void)out_size; (void)ws_size;
  const float* query = (const float*)d_in[0];
  const float* key   = (const float*)d_in[1];
  const float* value = (const float*)d_in[2];
  const float* q_w = (const float*)d_in[3];
  const float* q_b = (const float*)d_in[4];
  const float* k_w = (const float*)d_in[5];
  const float* k_b = (const float*)d_in[6];
  const float* v_w = (const float*)d_in[7];
  const float* v_b = (const float*)d_in[8];
  const float* o_w = (const float*)d_in[9];
  const float* o_b = (const float*)d_in[10];

  u16* ws = (u16*)d_ws;
  const size_t NX = (size_t)MROWS * EDIM;  // 4M
  const size_t NW = (size_t)EDIM * EDIM;   // 1M
  u16* Xq = ws;
  u16* Xk = Xq + NX;
  u16* Xv = Xk + NX;
  u16* Wq = Xv + NX;
  u16* Wk = Wq + NW;
  u16* Wv = Wk + NW;
  u16* Wo = Wv + NW;
  u16* Qp = Wo + NW;
  u16* Kp = Qp + NX;
  u16* Vp = Kp + NX;
  u16* At = Xq;  // overlay: Xq dead after Q projection

  cvt_flat_kernel<<<8192, 256, 0, stream>>>(
      query, key, value, q_w, k_w, v_w, o_w,
      Xq, Xk, Xv, Wq, Wk, Wv, Wo);

  gemm_qkv<<<dim3(8, 32, 3), 256, 0, stream>>>(
      Xq, Xk, Xv, Wq, Wk, Wv, q_b, k_b, v_b, Qp, Kp, Vp);

  attn3_kernel<<<512, 512, 0, stream>>>(Qp, Kp, Vp, At);

  gemm_oproj<<<dim3(16, 32), 256, 0, stream>>>(At, Wo, o_b, (float*)d_out);
}